// Round 1
// baseline (1695.545 us; speedup 1.0000x reference)
//
#include <hip/hip_runtime.h>
#include <hip/hip_bf16.h>
#include <math.h>

#define DIMM  512
#define NSEQ  1024
#define NHEAD 8
#define DH    64
#define DFF   2048
#define NVOC  32000
#define NDEPTH 2

// ---------------------------------------------------------------- embed
__global__ void embed_kernel(const int* __restrict__ tokens,
                             const float* __restrict__ temb,
                             const float* __restrict__ pemb,
                             float* __restrict__ x) {
    int i = blockIdx.x;
    int tok = tokens[i];
    const float* e = temb + (size_t)tok * DIMM;
    const float* p = pemb + (size_t)i * DIMM;
    float* xr = x + (size_t)i * DIMM;
    for (int d = threadIdx.x; d < DIMM; d += blockDim.x)
        xr[d] = e[d] + p[d];
}

// ---------------------------------------------------------------- rmsnorm
__global__ void rmsnorm_kernel(const float* __restrict__ x,
                               const float* __restrict__ gamma,
                               float* __restrict__ y) {
    int i = blockIdx.x;
    const float* xr = x + (size_t)i * DIMM;
    float ss = 0.f;
    for (int d = threadIdx.x; d < DIMM; d += 256) { float v = xr[d]; ss += v * v; }
    __shared__ float red[4];
    #pragma unroll
    for (int off = 32; off; off >>= 1) ss += __shfl_down(ss, off, 64);
    if ((threadIdx.x & 63) == 0) red[threadIdx.x >> 6] = ss;
    __syncthreads();
    float tot = red[0] + red[1] + red[2] + red[3];
    float norm = sqrtf(tot);
    float scale = 22.627416997969522f / fmaxf(norm, 1e-12f); // sqrt(512)/max(n,eps)
    float* yr = y + (size_t)i * DIMM;
    for (int d = threadIdx.x; d < DIMM; d += 256)
        yr[d] = xr[d] * scale * (gamma[d] + 1.0f);
}

// ---------------------------------------------------------------- row sum of squares
__global__ void rowsumsq_kernel(const float* __restrict__ x, int d,
                                float* __restrict__ out) {
    int i = blockIdx.x;
    const float* xr = x + (size_t)i * d;
    float ss = 0.f;
    for (int j = threadIdx.x; j < d; j += 256) { float v = xr[j]; ss += v * v; }
    __shared__ float red[4];
    #pragma unroll
    for (int off = 32; off; off >>= 1) ss += __shfl_down(ss, off, 64);
    if ((threadIdx.x & 63) == 0) red[threadIdx.x >> 6] = ss;
    __syncthreads();
    if (threadIdx.x == 0) out[i] = red[0] + red[1] + red[2] + red[3];
}

// ---------------------------------------------------------------- tiled GEMM  C[i][j] = f(A[i]·W[j])
// A [n,K] row-major, W [M,K] row-major (i.e. B^T). 64x64 tile, 256 thr, 4x4/thr.
enum { MODE_LINEAR = 0, MODE_CDIST = 1, MODE_FFGELU = 2, MODE_LOGITS = 3 };

template<int MODE>
__launch_bounds__(256)
__global__ void gemm_bt(const float* __restrict__ A, const float* __restrict__ W,
                        const float* __restrict__ xs, const float* __restrict__ ws,
                        const float* __restrict__ bias, const float* __restrict__ resid,
                        float* __restrict__ C, int K, int M) {
    __shared__ float As[16][68];   // stride 68: 16B-aligned ty*4 reads, write bank = (4kk+row)%32 -> 2-way max
    __shared__ float Bs[16][68];
    int tid = threadIdx.x;
    int tx = tid & 15, ty = tid >> 4;
    int row0 = blockIdx.y * 64;
    int col0 = blockIdx.x * 64;
    int lkk = tid & 15;
    int lr  = tid >> 4;
    float acc[4][4] = {};
    for (int k0 = 0; k0 < K; k0 += 16) {
        #pragma unroll
        for (int q = 0; q < 4; q++) {
            int r = lr + q * 16;
            As[lkk][r] = A[(size_t)(row0 + r) * K + k0 + lkk];
            Bs[lkk][r] = W[(size_t)(col0 + r) * K + k0 + lkk];
        }
        __syncthreads();
        #pragma unroll
        for (int kk = 0; kk < 16; kk++) {
            float a[4], b[4];
            #pragma unroll
            for (int i = 0; i < 4; i++) a[i] = As[kk][ty * 4 + i];
            #pragma unroll
            for (int j = 0; j < 4; j++) b[j] = Bs[kk][tx * 4 + j];
            #pragma unroll
            for (int i = 0; i < 4; i++)
                #pragma unroll
                for (int j = 0; j < 4; j++)
                    acc[i][j] = fmaf(a[i], b[j], acc[i][j]);
        }
        __syncthreads();
    }
    #pragma unroll
    for (int i = 0; i < 4; i++) {
        int r = row0 + ty * 4 + i;
        #pragma unroll
        for (int j = 0; j < 4; j++) {
            int c = col0 + tx * 4 + j;
            float dot = acc[i][j];
            float v;
            if (MODE == MODE_LINEAR) {
                v = dot;
                if (resid) v += resid[(size_t)r * M + c];
            } else {
                float d2 = xs[r] + ws[c] - 2.0f * dot;
                if (MODE == MODE_CDIST) {
                    v = sqrtf(fmaxf(d2, 0.0f));
                } else if (MODE == MODE_FFGELU) {
                    float hh = -d2 + bias[c];
                    v = 0.5f * hh * (1.0f + erff(hh * 0.70710678118654752f));
                } else { // LOGITS
                    v = -d2;
                }
            }
            C[(size_t)r * M + c] = v;
        }
    }
}

// ---------------------------------------------------------------- attention
// one block per (query i, head h). qkv row layout: [q(8x64) | k(8x64) | v(8x64)]
__global__ void attn_kernel(const float* __restrict__ qkv, float* __restrict__ o) {
    int i = blockIdx.x;
    int h = blockIdx.y;
    int tid = threadIdx.x; // 256
    __shared__ float q[DH];
    __shared__ float s[NSEQ];
    __shared__ float red[4];
    __shared__ float po[4][DH];
    const float* qrow = qkv + (size_t)i * 1536 + h * DH;
    if (tid < DH) q[tid] = qrow[tid];
    __syncthreads();
    float qs = 0.f;
    #pragma unroll
    for (int d = 0; d < DH; d++) qs += q[d] * q[d];
    // scores: sim = (2 q.k - |q|^2 - |k|^2) / sqrt(64)
    float lmax = -1e30f;
    for (int j = tid; j < NSEQ; j += 256) {
        const float* krow = qkv + (size_t)j * 1536 + 512 + h * DH;
        float dot = 0.f, ks = 0.f;
        #pragma unroll
        for (int d = 0; d < DH; d++) { float kv = krow[d]; dot += q[d] * kv; ks += kv * kv; }
        float sim = (2.0f * dot - qs - ks) * 0.125f;
        s[j] = sim;
        lmax = fmaxf(lmax, sim);
    }
    #pragma unroll
    for (int off = 32; off; off >>= 1) lmax = fmaxf(lmax, __shfl_down(lmax, off, 64));
    if ((tid & 63) == 0) red[tid >> 6] = lmax;
    __syncthreads();
    float m = fmaxf(fmaxf(red[0], red[1]), fmaxf(red[2], red[3]));
    float lsum = 0.f;
    for (int j = tid; j < NSEQ; j += 256) {
        float p = expf(s[j] - m);
        s[j] = p;
        lsum += p;
    }
    #pragma unroll
    for (int off = 32; off; off >>= 1) lsum += __shfl_down(lsum, off, 64);
    __syncthreads();                    // red reuse + make s[] exp values visible
    if ((tid & 63) == 0) red[tid >> 6] = lsum;
    __syncthreads();
    float sum = red[0] + red[1] + red[2] + red[3];
    // o[dh] = sum_j p_j v[j][dh] / sum
    int dh = tid & 63, g = tid >> 6;
    float acc = 0.f;
    for (int j = g * 256; j < (g + 1) * 256; j++)
        acc += s[j] * qkv[(size_t)j * 1536 + 1024 + h * DH + dh];
    po[g][dh] = acc;
    __syncthreads();
    if (tid < DH) {
        float v = (po[0][tid] + po[1][tid] + po[2][tid] + po[3][tid]) / sum;
        o[(size_t)i * DIMM + h * DH + tid] = v;
    }
}

// ---------------------------------------------------------------- launch
extern "C" void kernel_launch(void* const* d_in, const int* in_sizes, int n_in,
                              void* d_out, int out_size, void* d_ws, size_t ws_size,
                              hipStream_t stream) {
    (void)in_sizes; (void)n_in; (void)out_size; (void)ws_size;
    const int*   tokens      = (const int*)d_in[0];
    const float* temb        = (const float*)d_in[1];
    const float* pemb        = (const float*)d_in[2];
    const float* qkv_w       = (const float*)d_in[3];
    const float* attn_out_w  = (const float*)d_in[4];
    const float* ff_in_w     = (const float*)d_in[5];
    const float* ff_in_b     = (const float*)d_in[6];
    const float* ff_out_w    = (const float*)d_in[7];
    const float* attn_gamma  = (const float*)d_in[8];
    const float* ff_gamma    = (const float*)d_in[9];
    const float* final_gamma = (const float*)d_in[10];
    float* out = (float*)d_out;

    float* x   = (float*)d_ws;            // [1024,512]
    float* y   = x   + NSEQ * DIMM;       // [1024,512]
    float* qkv = y   + NSEQ * DIMM;       // [1024,1536]
    float* o   = qkv + NSEQ * 3 * DIMM;   // [1024,512]
    float* hb  = o   + NSEQ * DIMM;       // [1024,2048]
    float* xs  = hb  + NSEQ * DFF;        // [1024]
    float* wsq = xs  + NSEQ;              // [32000]

    embed_kernel<<<NSEQ, 256, 0, stream>>>(tokens, temb, pemb, x);

    for (int l = 0; l < NDEPTH; l++) {
        const float* qkvw = qkv_w      + (size_t)l * 3 * DIMM * DIMM;
        const float* aow  = attn_out_w + (size_t)l * DIMM * DIMM;
        const float* fiw  = ff_in_w    + (size_t)l * DFF * DIMM;
        const float* fib  = ff_in_b    + (size_t)l * DFF;
        const float* fow  = ff_out_w   + (size_t)l * DIMM * DFF;

        // --- attention block
        rmsnorm_kernel<<<NSEQ, 256, 0, stream>>>(x, attn_gamma + l * DIMM, y);
        rowsumsq_kernel<<<NSEQ, 256, 0, stream>>>(y, DIMM, xs);
        rowsumsq_kernel<<<3 * DIMM, 256, 0, stream>>>(qkvw, DIMM, wsq);
        gemm_bt<MODE_CDIST><<<dim3(3 * DIMM / 64, NSEQ / 64), 256, 0, stream>>>(
            y, qkvw, xs, wsq, nullptr, nullptr, qkv, DIMM, 3 * DIMM);
        attn_kernel<<<dim3(NSEQ, NHEAD), 256, 0, stream>>>(qkv, o);
        gemm_bt<MODE_LINEAR><<<dim3(DIMM / 64, NSEQ / 64), 256, 0, stream>>>(
            o, aow, nullptr, nullptr, nullptr, x, x, DIMM, DIMM);   // x += o @ W^T (in-place resid)

        // --- feedforward block
        rmsnorm_kernel<<<NSEQ, 256, 0, stream>>>(x, ff_gamma + l * DIMM, y);
        rowsumsq_kernel<<<NSEQ, 256, 0, stream>>>(y, DIMM, xs);
        rowsumsq_kernel<<<DFF, 256, 0, stream>>>(fiw, DIMM, wsq);
        gemm_bt<MODE_FFGELU><<<dim3(DFF / 64, NSEQ / 64), 256, 0, stream>>>(
            y, fiw, xs, wsq, fib, nullptr, hb, DIMM, DFF);
        gemm_bt<MODE_LINEAR><<<dim3(DIMM / 64, NSEQ / 64), 256, 0, stream>>>(
            hb, fow, nullptr, nullptr, nullptr, x, x, DFF, DIMM);   // x += h @ W^T
    }

    // --- final norm + logits = -sq_dist(x, token_emb)
    rmsnorm_kernel<<<NSEQ, 256, 0, stream>>>(x, final_gamma, y);
    rowsumsq_kernel<<<NSEQ, 256, 0, stream>>>(y, DIMM, xs);
    rowsumsq_kernel<<<NVOC, 256, 0, stream>>>(temb, DIMM, wsq);
    gemm_bt<MODE_LOGITS><<<dim3(NVOC / 64, NSEQ / 64), 256, 0, stream>>>(
        y, temb, xs, wsq, nullptr, nullptr, out, DIMM, NVOC);
}

// Round 2
// 1321.654 us; speedup vs baseline: 1.2829x; 1.2829x over previous
//
#include <hip/hip_runtime.h>
#include <math.h>

#define DIMM  512
#define NSEQ  1024
#define NHEAD 8
#define DH    64
#define DFF   2048
#define NVOC  32000
#define NDEPTH 2
#define QB    8

typedef __attribute__((ext_vector_type(8))) __bf16 bf16x8;
typedef __attribute__((ext_vector_type(4))) float f32x4;

__device__ __forceinline__ void g2l16(const void* g, void* l) {
    __builtin_amdgcn_global_load_lds(
        (const __attribute__((address_space(1))) void*)g,
        (__attribute__((address_space(3))) void*)l, 16, 0, 0);
}

// ---------------------------------------------------------------- embed
__global__ void embed_kernel(const int* __restrict__ tokens,
                             const float* __restrict__ temb,
                             const float* __restrict__ pemb,
                             float* __restrict__ x) {
    int i = blockIdx.x;
    int tok = tokens[i];
    const float* e = temb + (size_t)tok * DIMM;
    const float* p = pemb + (size_t)i * DIMM;
    float* xr = x + (size_t)i * DIMM;
    for (int d = threadIdx.x; d < DIMM; d += blockDim.x)
        xr[d] = e[d] + p[d];
}

// ---------------------------------------------------------------- rmsnorm -> bf16 + row sumsq
__global__ void rmsnorm_bf16(const float* __restrict__ x, const float* __restrict__ gamma,
                             __bf16* __restrict__ y, float* __restrict__ xs) {
    int i = blockIdx.x;
    int tid = threadIdx.x; // 256
    const float* xr = x + (size_t)i * DIMM;
    float v0 = xr[tid], v1 = xr[tid + 256];
    float ss = v0 * v0 + v1 * v1;
    __shared__ float red[4];
    #pragma unroll
    for (int off = 32; off; off >>= 1) ss += __shfl_down(ss, off, 64);
    if ((tid & 63) == 0) red[tid >> 6] = ss;
    __syncthreads();
    float tot = red[0] + red[1] + red[2] + red[3];
    float scale = 22.627416997969522f / fmaxf(sqrtf(tot), 1e-12f);
    float y0 = v0 * scale * (gamma[tid] + 1.0f);
    float y1 = v1 * scale * (gamma[tid + 256] + 1.0f);
    y[(size_t)i * DIMM + tid]       = (__bf16)y0;
    y[(size_t)i * DIMM + tid + 256] = (__bf16)y1;
    float s2 = y0 * y0 + y1 * y1;
    __syncthreads();
    #pragma unroll
    for (int off = 32; off; off >>= 1) s2 += __shfl_down(s2, off, 64);
    if ((tid & 63) == 0) red[tid >> 6] = s2;
    __syncthreads();
    if (tid == 0) xs[i] = red[0] + red[1] + red[2] + red[3];
}

// ---------------------------------------------------------------- f32 -> bf16 convert + optional row sumsq
__global__ void conv_sumsq(const float* __restrict__ src, __bf16* __restrict__ dst,
                           float* __restrict__ ssq, int K) {
    int row = blockIdx.x;
    const float* s = src + (size_t)row * K;
    __bf16* d = dst + (size_t)row * K;
    float ss = 0.f;
    for (int j = threadIdx.x; j < K; j += 256) {
        float v = s[j];
        d[j] = (__bf16)v;
        ss += v * v;
    }
    __shared__ float red[4];
    #pragma unroll
    for (int off = 32; off; off >>= 1) ss += __shfl_down(ss, off, 64);
    if ((threadIdx.x & 63) == 0) red[threadIdx.x >> 6] = ss;
    __syncthreads();
    if (threadIdx.x == 0 && ssq) ssq[row] = red[0] + red[1] + red[2] + red[3];
}

// ---------------------------------------------------------------- MFMA GEMM, 128x128 tile, BK=32
// C[i][j] = f(A[i]·W[j]); A [n,K], W [M,K] both row-major bf16.
enum { MODE_LINEAR = 0, MODE_CDIST = 1, MODE_FFGELU = 2, MODE_LOGITS = 3 };

template<int MODE>
__launch_bounds__(256)
__global__ void gemm_mfma(const __bf16* __restrict__ A, const __bf16* __restrict__ W,
                          const float* __restrict__ xs, const float* __restrict__ ws,
                          const float* __restrict__ bias, const float* __restrict__ resid,
                          void* __restrict__ Cout, int K, int M) {
    __shared__ __align__(16) __bf16 As[128 * 32];
    __shared__ __align__(16) __bf16 Bs[128 * 32];
    const int tid = threadIdx.x;
    const int lane = tid & 63;
    const int wv = tid >> 6;
    const int wr = wv >> 1, wc = wv & 1;
    const int row0 = blockIdx.y * 128;
    const int col0 = blockIdx.x * 128;
    const int srow = tid >> 2;
    const int scol = (tid & 3) * 8;
    const __bf16* gA = A + (size_t)(row0 + srow) * K + scol;
    const __bf16* gB = W + (size_t)(col0 + srow) * K + scol;
    const int lrow = lane & 15;
    const int lk8 = (lane >> 4) * 8;

    f32x4 acc[4][4] = {};
    for (int k0 = 0; k0 < K; k0 += 32) {
        g2l16(gA + k0,                 &As[tid * 8]);
        g2l16(gA + (size_t)64 * K + k0, &As[2048 + tid * 8]);
        g2l16(gB + k0,                 &Bs[tid * 8]);
        g2l16(gB + (size_t)64 * K + k0, &Bs[2048 + tid * 8]);
        __syncthreads();
        bf16x8 af[4], bfr[4];
        #pragma unroll
        for (int m = 0; m < 4; m++)
            af[m] = *(const bf16x8*)&As[(wr * 64 + m * 16 + lrow) * 32 + lk8];
        #pragma unroll
        for (int n = 0; n < 4; n++)
            bfr[n] = *(const bf16x8*)&Bs[(wc * 64 + n * 16 + lrow) * 32 + lk8];
        #pragma unroll
        for (int m = 0; m < 4; m++)
            #pragma unroll
            for (int n = 0; n < 4; n++)
                acc[m][n] = __builtin_amdgcn_mfma_f32_16x16x32_bf16(af[m], bfr[n], acc[m][n], 0, 0, 0);
        __syncthreads();
    }

    const int r_base = row0 + wr * 64 + (lane >> 4) * 4;
    const int c_base = col0 + wc * 64 + (lane & 15);
    #pragma unroll
    for (int m = 0; m < 4; m++) {
        #pragma unroll
        for (int j = 0; j < 4; j++) {
            const int r = r_base + m * 16 + j;
            const float xsr = (MODE == MODE_LINEAR) ? 0.f : xs[r];
            #pragma unroll
            for (int n = 0; n < 4; n++) {
                const int c = c_base + n * 16;
                const float dot = acc[m][n][j];
                if (MODE == MODE_LINEAR) {
                    float v = dot;
                    if (resid) v += resid[(size_t)r * M + c];
                    ((float*)Cout)[(size_t)r * M + c] = v;
                } else if (MODE == MODE_CDIST) {
                    float d2 = xsr + ws[c] - 2.0f * dot;
                    ((float*)Cout)[(size_t)r * M + c] = sqrtf(fmaxf(d2, 0.0f));
                } else if (MODE == MODE_FFGELU) {
                    float d2 = xsr + ws[c] - 2.0f * dot;
                    float hh = -d2 + bias[c];
                    float v = 0.5f * hh * (1.0f + erff(hh * 0.70710678118654752f));
                    ((__bf16*)Cout)[(size_t)r * M + c] = (__bf16)v;
                } else { // LOGITS
                    float d2 = xsr + ws[c] - 2.0f * dot;
                    ((float*)Cout)[(size_t)r * M + c] = -d2;
                }
            }
        }
    }
}

// ---------------------------------------------------------------- attention (fp32), 8 queries/block
__global__ void attn_kernel(const float* __restrict__ qkv, __bf16* __restrict__ o) {
    const int h = blockIdx.y;
    const int q0 = blockIdx.x * QB;
    const int tid = threadIdx.x;
    const int lane = tid & 63, wv = tid >> 6;
    __shared__ float q_s[QB][DH];
    __shared__ float qs_s[QB];
    __shared__ float s[QB][NSEQ];    // 32 KB
    __shared__ float red[QB][4];
    __shared__ float mx[QB], sm[QB];
    __shared__ float po[4][QB][DH];  // 8 KB

    for (int t = tid; t < QB * DH; t += 256)
        q_s[t >> 6][t & 63] = qkv[(size_t)(q0 + (t >> 6)) * 1536 + h * DH + (t & 63)];
    __syncthreads();
    if (tid < QB) {
        float a = 0.f;
        #pragma unroll
        for (int d = 0; d < DH; d++) a += q_s[tid][d] * q_s[tid][d];
        qs_s[tid] = a;
    }
    __syncthreads();

    float lmax[QB];
    #pragma unroll
    for (int q = 0; q < QB; q++) lmax[q] = -1e30f;
    for (int j = tid; j < NSEQ; j += 256) {
        const float4* kr = (const float4*)(qkv + (size_t)j * 1536 + 512 + h * DH);
        float dot[QB] = {};
        float ks = 0.f;
        #pragma unroll
        for (int d4 = 0; d4 < DH / 4; d4++) {
            float4 kv = kr[d4];
            ks += kv.x * kv.x + kv.y * kv.y + kv.z * kv.z + kv.w * kv.w;
            #pragma unroll
            for (int q = 0; q < QB; q++)
                dot[q] += q_s[q][d4 * 4] * kv.x + q_s[q][d4 * 4 + 1] * kv.y
                        + q_s[q][d4 * 4 + 2] * kv.z + q_s[q][d4 * 4 + 3] * kv.w;
        }
        #pragma unroll
        for (int q = 0; q < QB; q++) {
            float sim = (2.0f * dot[q] - qs_s[q] - ks) * 0.125f;
            s[q][j] = sim;
            lmax[q] = fmaxf(lmax[q], sim);
        }
    }
    #pragma unroll
    for (int q = 0; q < QB; q++) {
        float v = lmax[q];
        #pragma unroll
        for (int off = 32; off; off >>= 1) v = fmaxf(v, __shfl_down(v, off, 64));
        if (lane == 0) red[q][wv] = v;
    }
    __syncthreads();
    if (tid < QB) mx[tid] = fmaxf(fmaxf(red[tid][0], red[tid][1]), fmaxf(red[tid][2], red[tid][3]));
    __syncthreads();

    float lsum[QB] = {};
    for (int j = tid; j < NSEQ; j += 256) {
        #pragma unroll
        for (int q = 0; q < QB; q++) {
            float p = expf(s[q][j] - mx[q]);
            s[q][j] = p;
            lsum[q] += p;
        }
    }
    #pragma unroll
    for (int q = 0; q < QB; q++) {
        float v = lsum[q];
        #pragma unroll
        for (int off = 32; off; off >>= 1) v += __shfl_down(v, off, 64);
        if (lane == 0) red[q][wv] = v;
    }
    __syncthreads();
    if (tid < QB) sm[tid] = red[tid][0] + red[tid][1] + red[tid][2] + red[tid][3];
    __syncthreads();

    float acc[QB] = {};
    for (int j = wv * 256; j < (wv + 1) * 256; j++) {
        float v = qkv[(size_t)j * 1536 + 1024 + h * DH + lane];
        #pragma unroll
        for (int q = 0; q < QB; q++) acc[q] += s[q][j] * v;
    }
    #pragma unroll
    for (int q = 0; q < QB; q++) po[wv][q][lane] = acc[q];
    __syncthreads();
    for (int t = tid; t < QB * DH; t += 256) {
        int q = t >> 6, d = t & 63;
        float v = (po[0][q][d] + po[1][q][d] + po[2][q][d] + po[3][q][d]) / sm[q];
        o[(size_t)(q0 + q) * DIMM + h * DH + d] = (__bf16)v;
    }
}

// ---------------------------------------------------------------- launch
extern "C" void kernel_launch(void* const* d_in, const int* in_sizes, int n_in,
                              void* d_out, int out_size, void* d_ws, size_t ws_size,
                              hipStream_t stream) {
    (void)in_sizes; (void)n_in; (void)out_size; (void)ws_size;
    const int*   tokens      = (const int*)d_in[0];
    const float* temb        = (const float*)d_in[1];
    const float* pemb        = (const float*)d_in[2];
    const float* qkv_w       = (const float*)d_in[3];
    const float* attn_out_w  = (const float*)d_in[4];
    const float* ff_in_w     = (const float*)d_in[5];
    const float* ff_in_b     = (const float*)d_in[6];
    const float* ff_out_w    = (const float*)d_in[7];
    const float* attn_gamma  = (const float*)d_in[8];
    const float* ff_gamma    = (const float*)d_in[9];
    const float* final_gamma = (const float*)d_in[10];
    float* out = (float*)d_out;

    char* p = (char*)d_ws;
    float*  x        = (float*)p;           p += (size_t)NSEQ * DIMM * 4;          // 2 MB
    float*  qkv      = (float*)p;           p += (size_t)NSEQ * 3 * DIMM * 4;      // 6 MB
    float*  xs       = (float*)p;           p += (size_t)NSEQ * 4;
    float*  wsq_qkv  = (float*)p;           p += (size_t)NDEPTH * 3 * DIMM * 4;
    float*  wsq_ff   = (float*)p;           p += (size_t)NDEPTH * DFF * 4;
    float*  wsq_temb = (float*)p;           p += (size_t)NVOC * 4;
    __bf16* y16      = (__bf16*)p;          p += (size_t)NSEQ * DIMM * 2;          // 1 MB
    __bf16* o16      = (__bf16*)p;          p += (size_t)NSEQ * DIMM * 2;          // 1 MB
    __bf16* hb16     = (__bf16*)p;          p += (size_t)NSEQ * DFF * 2;           // 4 MB
    __bf16* wq16     = (__bf16*)p;          p += (size_t)NDEPTH * 3 * DIMM * DIMM * 2;
    __bf16* wa16     = (__bf16*)p;          p += (size_t)NDEPTH * DIMM * DIMM * 2;
    __bf16* wfi16    = (__bf16*)p;          p += (size_t)NDEPTH * DFF * DIMM * 2;
    __bf16* wfo16    = (__bf16*)p;          p += (size_t)NDEPTH * DIMM * DFF * 2;
    __bf16* temb16   = (__bf16*)p;          p += (size_t)NVOC * DIMM * 2;          // 32.8 MB

    // weight conversions (per-launch; deterministic)
    conv_sumsq<<<NDEPTH * 3 * DIMM, 256, 0, stream>>>(qkv_w, wq16, wsq_qkv, DIMM);
    conv_sumsq<<<NDEPTH * DIMM,     256, 0, stream>>>(attn_out_w, wa16, nullptr, DIMM);
    conv_sumsq<<<NDEPTH * DFF,      256, 0, stream>>>(ff_in_w, wfi16, wsq_ff, DIMM);
    conv_sumsq<<<NDEPTH * DIMM,     256, 0, stream>>>(ff_out_w, wfo16, nullptr, DFF);
    conv_sumsq<<<NVOC,              256, 0, stream>>>(temb, temb16, wsq_temb, DIMM);

    embed_kernel<<<NSEQ, 256, 0, stream>>>(tokens, temb, pemb, x);

    for (int l = 0; l < NDEPTH; l++) {
        const __bf16* qkvw = wq16  + (size_t)l * 3 * DIMM * DIMM;
        const __bf16* aow  = wa16  + (size_t)l * DIMM * DIMM;
        const __bf16* fiw  = wfi16 + (size_t)l * DFF * DIMM;
        const __bf16* fow  = wfo16 + (size_t)l * DIMM * DFF;
        const float*  fib  = ff_in_b + (size_t)l * DFF;

        // --- attention block
        rmsnorm_bf16<<<NSEQ, 256, 0, stream>>>(x, attn_gamma + l * DIMM, y16, xs);
        gemm_mfma<MODE_CDIST><<<dim3(3 * DIMM / 128, NSEQ / 128), 256, 0, stream>>>(
            y16, qkvw, xs, wsq_qkv + l * 3 * DIMM, nullptr, nullptr, qkv, DIMM, 3 * DIMM);
        attn_kernel<<<dim3(NSEQ / QB, NHEAD), 256, 0, stream>>>(qkv, o16);
        gemm_mfma<MODE_LINEAR><<<dim3(DIMM / 128, NSEQ / 128), 256, 0, stream>>>(
            o16, aow, nullptr, nullptr, nullptr, x, x, DIMM, DIMM);

        // --- feedforward block
        rmsnorm_bf16<<<NSEQ, 256, 0, stream>>>(x, ff_gamma + l * DIMM, y16, xs);
        gemm_mfma<MODE_FFGELU><<<dim3(DFF / 128, NSEQ / 128), 256, 0, stream>>>(
            y16, fiw, xs, wsq_ff + l * DFF, fib, nullptr, hb16, DIMM, DFF);
        gemm_mfma<MODE_LINEAR><<<dim3(DIMM / 128, NSEQ / 128), 256, 0, stream>>>(
            hb16, fow, nullptr, nullptr, nullptr, x, x, DFF, DIMM);
    }

    // --- final norm + logits
    rmsnorm_bf16<<<NSEQ, 256, 0, stream>>>(x, final_gamma, y16, xs);
    gemm_mfma<MODE_LOGITS><<<dim3(NVOC / 128, NSEQ / 128), 256, 0, stream>>>(
        y16, temb16, xs, wsq_temb, nullptr, nullptr, out, DIMM, NVOC);
}

// Round 3
// 485.424 us; speedup vs baseline: 3.4929x; 2.7227x over previous
//
#include <hip/hip_runtime.h>
#include <math.h>

#define DIMM  512
#define NSEQ  1024
#define NHEAD 8
#define DH    64
#define DFF   2048
#define NVOC  32000
#define NDEPTH 2
#define VCENTER 32.0f

typedef __attribute__((ext_vector_type(8))) __bf16 bf16x8;
typedef __attribute__((ext_vector_type(4))) __bf16 bf16x4;
typedef __attribute__((ext_vector_type(4))) float f32x4;

__device__ __forceinline__ void g2l16(const void* g, void* l) {
    __builtin_amdgcn_global_load_lds(
        (const __attribute__((address_space(1))) void*)g,
        (__attribute__((address_space(3))) void*)l, 16, 0, 0);
}

// ---------------------------------------------------------------- embed
__launch_bounds__(256)
__global__ void embed_kernel(const int* __restrict__ tokens,
                             const float* __restrict__ temb,
                             const float* __restrict__ pemb,
                             float* __restrict__ x) {
    int i = blockIdx.x;
    int tok = tokens[i];
    const float* e = temb + (size_t)tok * DIMM;
    const float* p = pemb + (size_t)i * DIMM;
    float* xr = x + (size_t)i * DIMM;
    for (int d = threadIdx.x; d < DIMM; d += blockDim.x)
        xr[d] = e[d] + p[d];
}

// ---------------------------------------------------------------- rmsnorm -> bf16 + row sumsq
__launch_bounds__(256)
__global__ void rmsnorm_bf16(const float* __restrict__ x, const float* __restrict__ gamma,
                             __bf16* __restrict__ y, float* __restrict__ xs) {
    int i = blockIdx.x;
    int tid = threadIdx.x; // 256
    const float* xr = x + (size_t)i * DIMM;
    float v0 = xr[tid], v1 = xr[tid + 256];
    float ss = v0 * v0 + v1 * v1;
    __shared__ float red[4];
    #pragma unroll
    for (int off = 32; off; off >>= 1) ss += __shfl_down(ss, off, 64);
    if ((tid & 63) == 0) red[tid >> 6] = ss;
    __syncthreads();
    float tot = red[0] + red[1] + red[2] + red[3];
    float scale = 22.627416997969522f / fmaxf(sqrtf(tot), 1e-12f);
    float y0 = v0 * scale * (gamma[tid] + 1.0f);
    float y1 = v1 * scale * (gamma[tid + 256] + 1.0f);
    y[(size_t)i * DIMM + tid]       = (__bf16)y0;
    y[(size_t)i * DIMM + tid + 256] = (__bf16)y1;
    float s2 = y0 * y0 + y1 * y1;
    __syncthreads();
    #pragma unroll
    for (int off = 32; off; off >>= 1) s2 += __shfl_down(s2, off, 64);
    if ((tid & 63) == 0) red[tid >> 6] = s2;
    __syncthreads();
    if (tid == 0) xs[i] = red[0] + red[1] + red[2] + red[3];
}

// ---------------------------------------------------------------- f32 -> bf16 convert + optional row sumsq
__launch_bounds__(256)
__global__ void conv_sumsq(const float* __restrict__ src, __bf16* __restrict__ dst,
                           float* __restrict__ ssq, int K) {
    int row = blockIdx.x;
    const float* s = src + (size_t)row * K;
    __bf16* d = dst + (size_t)row * K;
    float ss = 0.f;
    for (int j = threadIdx.x; j < K; j += 256) {
        float v = s[j];
        d[j] = (__bf16)v;
        ss += v * v;
    }
    __shared__ float red[4];
    #pragma unroll
    for (int off = 32; off; off >>= 1) ss += __shfl_down(ss, off, 64);
    if ((threadIdx.x & 63) == 0) red[threadIdx.x >> 6] = ss;
    __syncthreads();
    if (threadIdx.x == 0 && ssq) ssq[row] = red[0] + red[1] + red[2] + red[3];
}

// ---------------------------------------------------------------- MFMA GEMM, 128x128 tile, BK=32
// C[i][j] = f(A[i]·W[j]); A [n,K], W [M,K] both row-major bf16.
enum { MODE_LINEAR = 0, MODE_CDIST = 1, MODE_FFGELU = 2, MODE_LOGITS = 3, MODE_SCORES = 4 };

template<int MODE>
__launch_bounds__(256)
__global__ void gemm_mfma(const __bf16* __restrict__ A, const __bf16* __restrict__ W,
                          const float* __restrict__ xs, const float* __restrict__ ws,
                          const float* __restrict__ bias, const float* __restrict__ resid,
                          void* __restrict__ Cout, int K, int M) {
    if (MODE == MODE_SCORES) {           // batched over heads
        const int z = blockIdx.z;
        A  += (size_t)z * NSEQ * DH;
        W  += (size_t)z * NSEQ * DH;
        xs += (size_t)z * NSEQ;
        ws += (size_t)z * NSEQ;
        Cout = (float*)Cout + (size_t)z * NSEQ * NSEQ;
    }
    __shared__ __align__(16) __bf16 As[128 * 32];
    __shared__ __align__(16) __bf16 Bs[128 * 32];
    const int tid = threadIdx.x;
    const int lane = tid & 63;
    const int wv = tid >> 6;
    const int wr = wv >> 1, wc = wv & 1;
    const int row0 = blockIdx.y * 128;
    const int col0 = blockIdx.x * 128;
    const int srow = tid >> 2;
    const int scol = (tid & 3) * 8;
    const __bf16* gA = A + (size_t)(row0 + srow) * K + scol;
    const __bf16* gB = W + (size_t)(col0 + srow) * K + scol;
    const int lrow = lane & 15;
    const int lk8 = (lane >> 4) * 8;

    f32x4 acc[4][4] = {};
    for (int k0 = 0; k0 < K; k0 += 32) {
        g2l16(gA + k0,                  &As[tid * 8]);
        g2l16(gA + (size_t)64 * K + k0, &As[2048 + tid * 8]);
        g2l16(gB + k0,                  &Bs[tid * 8]);
        g2l16(gB + (size_t)64 * K + k0, &Bs[2048 + tid * 8]);
        __syncthreads();
        bf16x8 af[4], bfr[4];
        #pragma unroll
        for (int m = 0; m < 4; m++)
            af[m] = *(const bf16x8*)&As[(wr * 64 + m * 16 + lrow) * 32 + lk8];
        #pragma unroll
        for (int n = 0; n < 4; n++)
            bfr[n] = *(const bf16x8*)&Bs[(wc * 64 + n * 16 + lrow) * 32 + lk8];
        #pragma unroll
        for (int m = 0; m < 4; m++)
            #pragma unroll
            for (int n = 0; n < 4; n++)
                acc[m][n] = __builtin_amdgcn_mfma_f32_16x16x32_bf16(af[m], bfr[n], acc[m][n], 0, 0, 0);
        __syncthreads();
    }

    const int r_base = row0 + wr * 64 + (lane >> 4) * 4;
    const int c_base = col0 + wc * 64 + (lane & 15);
    #pragma unroll
    for (int m = 0; m < 4; m++) {
        #pragma unroll
        for (int j = 0; j < 4; j++) {
            const int r = r_base + m * 16 + j;
            const float xsr = (MODE == MODE_LINEAR) ? 0.f : xs[r];
            #pragma unroll
            for (int n = 0; n < 4; n++) {
                const int c = c_base + n * 16;
                const float dot = acc[m][n][j];
                if (MODE == MODE_LINEAR) {
                    float v = dot;
                    if (resid) v += resid[(size_t)r * M + c];
                    ((float*)Cout)[(size_t)r * M + c] = v;
                } else if (MODE == MODE_CDIST) {
                    float d2 = xsr + ws[c] - 2.0f * dot;
                    ((float*)Cout)[(size_t)r * M + c] = sqrtf(fmaxf(d2, 0.0f));
                } else if (MODE == MODE_FFGELU) {
                    float d2 = xsr + ws[c] - 2.0f * dot;
                    float hh = -d2 + bias[c];
                    float v = 0.5f * hh * (1.0f + erff(hh * 0.70710678118654752f));
                    ((__bf16*)Cout)[(size_t)r * M + c] = (__bf16)v;
                } else if (MODE == MODE_SCORES) {
                    ((float*)Cout)[(size_t)r * M + c] = (2.0f * dot - xsr - ws[c]) * 0.125f;
                } else { // LOGITS
                    float d2 = xsr + ws[c] - 2.0f * dot;
                    ((float*)Cout)[(size_t)r * M + c] = -d2;
                }
            }
        }
    }
}

// ---------------------------------------------------------------- qkv split: center to bf16, sumsq, V transposed
__launch_bounds__(256)
__global__ void qkv_center(const float* __restrict__ qkv,
                           __bf16* __restrict__ Qc, __bf16* __restrict__ Kc,
                           __bf16* __restrict__ VcT,
                           float* __restrict__ qs, float* __restrict__ ks) {
    const int i = blockIdx.x;
    const int t = threadIdx.x;
    const int lane = t & 63, wv = t >> 6;
    const float* base = qkv + (size_t)i * 1536;
    #pragma unroll
    for (int g = 0; g < 2; g++) {
        const int col = g * 256 + t;        // 0..511
        const int h = g * 4 + wv;           // head = col>>6
        const int d = lane;                 // col&63
        __bf16 qb = (__bf16)(base[col] - VCENTER);
        __bf16 kb = (__bf16)(base[512 + col] - VCENTER);
        __bf16 vb = (__bf16)(base[1024 + col] - VCENTER);
        Qc[((size_t)h * NSEQ + i) * DH + d] = qb;
        Kc[((size_t)h * NSEQ + i) * DH + d] = kb;
        VcT[((size_t)h * DH + d) * NSEQ + i] = vb;
        float q2 = (float)qb * (float)qb;
        float k2 = (float)kb * (float)kb;
        #pragma unroll
        for (int off = 32; off; off >>= 1) {
            q2 += __shfl_down(q2, off, 64);
            k2 += __shfl_down(k2, off, 64);
        }
        if (lane == 0) {
            qs[(size_t)h * NSEQ + i] = q2;
            ks[(size_t)h * NSEQ + i] = k2;
        }
    }
}

// ---------------------------------------------------------------- softmax rows, in-place f32 -> bf16 (normalized)
__launch_bounds__(256)
__global__ void softmax_rows(float* __restrict__ S) {
    const size_t row = blockIdx.x;
    float* base = S + row * NSEQ;
    const int t = threadIdx.x;
    float4 v = ((const float4*)base)[t];
    float m = fmaxf(fmaxf(v.x, v.y), fmaxf(v.z, v.w));
    __shared__ float red[4];
    #pragma unroll
    for (int off = 32; off; off >>= 1) m = fmaxf(m, __shfl_down(m, off, 64));
    if ((t & 63) == 0) red[t >> 6] = m;
    __syncthreads();
    float mx = fmaxf(fmaxf(red[0], red[1]), fmaxf(red[2], red[3]));
    float e0 = expf(v.x - mx), e1 = expf(v.y - mx);
    float e2 = expf(v.z - mx), e3 = expf(v.w - mx);
    float s = e0 + e1 + e2 + e3;
    __syncthreads();
    #pragma unroll
    for (int off = 32; off; off >>= 1) s += __shfl_down(s, off, 64);
    if ((t & 63) == 0) red[t >> 6] = s;
    __syncthreads();
    float inv = 1.0f / (red[0] + red[1] + red[2] + red[3]);
    bf16x4 p;
    p.x = (__bf16)(e0 * inv); p.y = (__bf16)(e1 * inv);
    p.z = (__bf16)(e2 * inv); p.w = (__bf16)(e3 * inv);
    *(bf16x4*)((__bf16*)base + t * 4) = p;   // all reads done (2 barriers above)
}

// ---------------------------------------------------------------- PV: O[i][h*64+d] = P_h[i]·VcT_h[d] + 32
// P rows stride 2048 bf16 (in-place over f32 S). 128x64 tile per block.
__launch_bounds__(256)
__global__ void gemm_pv(const __bf16* __restrict__ Pall, const __bf16* __restrict__ VcT,
                        __bf16* __restrict__ O) {
    __shared__ __align__(16) __bf16 As[128 * 32];
    __shared__ __align__(16) __bf16 Bs[64 * 32];
    const int tid = threadIdx.x;
    const int lane = tid & 63;
    const int wv = tid >> 6;
    const int h = blockIdx.y;
    const int row0 = blockIdx.x * 128;
    const __bf16* A = Pall + (size_t)h * NSEQ * 2048;
    const __bf16* B = VcT + (size_t)h * DH * NSEQ;
    const int srow = tid >> 2;
    const int scol = (tid & 3) * 8;
    const __bf16* gA = A + (size_t)(row0 + srow) * 2048 + scol;
    const __bf16* gB = B + (size_t)srow * NSEQ + scol;
    const int lrow = lane & 15;
    const int lk8 = (lane >> 4) * 8;

    f32x4 acc[2][4] = {};
    for (int k0 = 0; k0 < NSEQ; k0 += 32) {
        g2l16(gA + k0,                     &As[tid * 8]);
        g2l16(gA + (size_t)64 * 2048 + k0, &As[2048 + tid * 8]);
        g2l16(gB + k0,                     &Bs[tid * 8]);
        __syncthreads();
        bf16x8 af[2], bfr[4];
        #pragma unroll
        for (int m = 0; m < 2; m++)
            af[m] = *(const bf16x8*)&As[(wv * 32 + m * 16 + lrow) * 32 + lk8];
        #pragma unroll
        for (int n = 0; n < 4; n++)
            bfr[n] = *(const bf16x8*)&Bs[(n * 16 + lrow) * 32 + lk8];
        #pragma unroll
        for (int m = 0; m < 2; m++)
            #pragma unroll
            for (int n = 0; n < 4; n++)
                acc[m][n] = __builtin_amdgcn_mfma_f32_16x16x32_bf16(af[m], bfr[n], acc[m][n], 0, 0, 0);
        __syncthreads();
    }

    #pragma unroll
    for (int m = 0; m < 2; m++) {
        #pragma unroll
        for (int j = 0; j < 4; j++) {
            const int r = row0 + wv * 32 + m * 16 + (lane >> 4) * 4 + j;
            #pragma unroll
            for (int n = 0; n < 4; n++) {
                const int d = n * 16 + (lane & 15);
                O[(size_t)r * DIMM + h * DH + d] = (__bf16)(acc[m][n][j] + VCENTER);
            }
        }
    }
}

// ---------------------------------------------------------------- launch
extern "C" void kernel_launch(void* const* d_in, const int* in_sizes, int n_in,
                              void* d_out, int out_size, void* d_ws, size_t ws_size,
                              hipStream_t stream) {
    (void)in_sizes; (void)n_in; (void)out_size; (void)ws_size;
    const int*   tokens      = (const int*)d_in[0];
    const float* temb        = (const float*)d_in[1];
    const float* pemb        = (const float*)d_in[2];
    const float* qkv_w       = (const float*)d_in[3];
    const float* attn_out_w  = (const float*)d_in[4];
    const float* ff_in_w     = (const float*)d_in[5];
    const float* ff_in_b     = (const float*)d_in[6];
    const float* ff_out_w    = (const float*)d_in[7];
    const float* attn_gamma  = (const float*)d_in[8];
    const float* ff_gamma    = (const float*)d_in[9];
    const float* final_gamma = (const float*)d_in[10];
    float* out = (float*)d_out;

    char* p = (char*)d_ws;
    float*  x        = (float*)p;  p += (size_t)NSEQ * DIMM * 4;            // 2 MB
    float*  qkv      = (float*)p;  p += (size_t)NSEQ * 3 * DIMM * 4;        // 6 MB
    float*  xs       = (float*)p;  p += (size_t)NSEQ * 4;
    float*  wsq_qkv  = (float*)p;  p += (size_t)NDEPTH * 3 * DIMM * 4;
    float*  wsq_ff   = (float*)p;  p += (size_t)NDEPTH * DFF * 4;
    float*  wsq_temb = (float*)p;  p += (size_t)NVOC * 4;
    __bf16* y16      = (__bf16*)p; p += (size_t)NSEQ * DIMM * 2;            // 1 MB
    __bf16* o16      = (__bf16*)p; p += (size_t)NSEQ * DIMM * 2;            // 1 MB
    float*  S        = (float*)p;  p += (size_t)NHEAD * NSEQ * NSEQ * 4;    // 32 MB
    // union region: hb16 (FF) aliases attention temporaries (time-disjoint)
    char* ureg = p;                p += (size_t)NSEQ * DFF * 2;             // 4 MB
    __bf16* hb16 = (__bf16*)ureg;
    __bf16* Qc   = (__bf16*)ureg;
    __bf16* Kc   = Qc + (size_t)NHEAD * NSEQ * DH;
    __bf16* VcT  = Kc + (size_t)NHEAD * NSEQ * DH;
    float*  qs   = (float*)(VcT + (size_t)NHEAD * NSEQ * DH);
    float*  ks   = qs + NHEAD * NSEQ;
    __bf16* wq16   = (__bf16*)p;   p += (size_t)NDEPTH * 3 * DIMM * DIMM * 2;
    __bf16* wa16   = (__bf16*)p;   p += (size_t)NDEPTH * DIMM * DIMM * 2;
    __bf16* wfi16  = (__bf16*)p;   p += (size_t)NDEPTH * DFF * DIMM * 2;
    __bf16* wfo16  = (__bf16*)p;   p += (size_t)NDEPTH * DIMM * DFF * 2;
    __bf16* temb16 = (__bf16*)p;   p += (size_t)NVOC * DIMM * 2;            // 32.8 MB

    // weight conversions (per-launch; deterministic)
    conv_sumsq<<<NDEPTH * 3 * DIMM, 256, 0, stream>>>(qkv_w, wq16, wsq_qkv, DIMM);
    conv_sumsq<<<NDEPTH * DIMM,     256, 0, stream>>>(attn_out_w, wa16, nullptr, DIMM);
    conv_sumsq<<<NDEPTH * DFF,      256, 0, stream>>>(ff_in_w, wfi16, wsq_ff, DIMM);
    conv_sumsq<<<NDEPTH * DIMM,     256, 0, stream>>>(ff_out_w, wfo16, nullptr, DFF);
    conv_sumsq<<<NVOC,              256, 0, stream>>>(temb, temb16, wsq_temb, DIMM);

    embed_kernel<<<NSEQ, 256, 0, stream>>>(tokens, temb, pemb, x);

    for (int l = 0; l < NDEPTH; l++) {
        const __bf16* qkvw = wq16  + (size_t)l * 3 * DIMM * DIMM;
        const __bf16* aow  = wa16  + (size_t)l * DIMM * DIMM;
        const __bf16* fiw  = wfi16 + (size_t)l * DFF * DIMM;
        const __bf16* fow  = wfo16 + (size_t)l * DIMM * DFF;
        const float*  fib  = ff_in_b + (size_t)l * DFF;

        // --- attention block
        rmsnorm_bf16<<<NSEQ, 256, 0, stream>>>(x, attn_gamma + l * DIMM, y16, xs);
        gemm_mfma<MODE_CDIST><<<dim3(3 * DIMM / 128, NSEQ / 128), 256, 0, stream>>>(
            y16, qkvw, xs, wsq_qkv + l * 3 * DIMM, nullptr, nullptr, qkv, DIMM, 3 * DIMM);
        qkv_center<<<NSEQ, 256, 0, stream>>>(qkv, Qc, Kc, VcT, qs, ks);
        gemm_mfma<MODE_SCORES><<<dim3(NSEQ / 128, NSEQ / 128, NHEAD), 256, 0, stream>>>(
            Qc, Kc, qs, ks, nullptr, nullptr, S, DH, NSEQ);
        softmax_rows<<<NHEAD * NSEQ, 256, 0, stream>>>(S);
        gemm_pv<<<dim3(NSEQ / 128, NHEAD), 256, 0, stream>>>((const __bf16*)S, VcT, o16);
        gemm_mfma<MODE_LINEAR><<<dim3(DIMM / 128, NSEQ / 128), 256, 0, stream>>>(
            o16, aow, nullptr, nullptr, nullptr, x, x, DIMM, DIMM);

        // --- feedforward block
        rmsnorm_bf16<<<NSEQ, 256, 0, stream>>>(x, ff_gamma + l * DIMM, y16, xs);
        gemm_mfma<MODE_FFGELU><<<dim3(DFF / 128, NSEQ / 128), 256, 0, stream>>>(
            y16, fiw, xs, wsq_ff + l * DFF, fib, nullptr, hb16, DIMM, DFF);
        gemm_mfma<MODE_LINEAR><<<dim3(DIMM / 128, NSEQ / 128), 256, 0, stream>>>(
            hb16, fow, nullptr, nullptr, nullptr, x, x, DFF, DIMM);
    }

    // --- final norm + logits
    rmsnorm_bf16<<<NSEQ, 256, 0, stream>>>(x, final_gamma, y16, xs);
    gemm_mfma<MODE_LOGITS><<<dim3(NVOC / 128, NSEQ / 128), 256, 0, stream>>>(
        y16, temb16, xs, wsq_temb, nullptr, nullptr, out, DIMM, NVOC);
}